// Round 2
// baseline (1422.852 us; speedup 1.0000x reference)
//
#include <hip/hip_runtime.h>

// GlobalEdgeGnn on MI355X (gfx950) — round 1.
// Changes vs round 0:
//  - Weights read as B-fragments directly from global (L2 broadcast) -> LDS 64KB->32KB/block,
//    occupancy 2 blocks/CU -> ~3-4 blocks/CU.
//  - Conv fused with aggregation: per-wave segmented reduce over CSR-sorted dst + f32 atomics
//    into xsum (removes 256MB/layer message traffic and k_agg).
//  - Faster two-pass shuffle scan for CSR offsets.

#define NN 50000
#define NE 500000
#define DE 1000000   // 2E directed
#define DD 64
#define HH 128

typedef __attribute__((ext_vector_type(8))) __bf16 bfrag;
typedef __attribute__((ext_vector_type(8))) short  svec8;
typedef __attribute__((ext_vector_type(4))) float  f32x4;

__device__ __forceinline__ unsigned short f2bf(float f){
  unsigned u = __builtin_bit_cast(unsigned, f);
  u += 0x7fffu + ((u >> 16) & 1u);          // RNE
  return (unsigned short)(u >> 16);
}
__device__ __forceinline__ float bf2f(unsigned short s){
  return __builtin_bit_cast(float, ((unsigned)s) << 16);
}
#define MFMA __builtin_amdgcn_mfma_f32_16x16x32_bf16

// ---------------- CSR build ----------------
__global__ void k_hist(const int* __restrict__ ei, int* __restrict__ cnt){
  int e = blockIdx.x*256 + threadIdx.x;
  if (e >= DE) return;
  int dst = (e < NE) ? ei[NE + e] : ei[e - NE];   // bi_dst
  atomicAdd(&cnt[dst], 1);
}

// two-pass scan: 1024 threads, 49 nodes/thread; shuffle scan of per-thread sums.
__global__ void k_scan(const int* __restrict__ cnt, int* __restrict__ off,
                       int* __restrict__ cur, float* __restrict__ dinv){
  __shared__ int wsum[16];
  const int CH = 49;                         // 1024*49 >= 50000
  int tid = threadIdx.x;
  int base = tid * CH;
  int s = 0;
  for (int i = 0; i < CH; i++){
    int idx = base + i;
    if (idx < NN) s += cnt[idx];
  }
  int lane = tid & 63, w = tid >> 6;
  int inc = s;
  for (int o2 = 1; o2 < 64; o2 <<= 1){
    int t = __shfl_up(inc, o2);
    if (lane >= o2) inc += t;
  }
  if (lane == 63) wsum[w] = inc;
  __syncthreads();
  if (tid < 16){
    int v = wsum[tid], p = v;
    for (int o2 = 1; o2 < 16; o2 <<= 1){
      int t = __shfl_up(p, o2, 16);
      if (tid >= o2) p += t;
    }
    wsum[tid] = p - v;                       // exclusive wave offsets
  }
  __syncthreads();
  int pre = wsum[w] + inc - s;               // exclusive prefix for this thread
  for (int i = 0; i < CH; i++){
    int idx = base + i;
    if (idx < NN){
      int v = cnt[idx];
      off[idx] = pre; cur[idx] = pre;
      dinv[idx] = 1.0f / (float)(v > 1 ? v : 1);
      pre += v;
    }
  }
  if (tid == 0) off[NN] = DE;
}

__global__ void k_fill(const int* __restrict__ ei, int* __restrict__ cur,
                       int* __restrict__ nbr, int* __restrict__ dstA, int* __restrict__ eid){
  int e = blockIdx.x*256 + threadIdx.x;
  if (e >= DE) return;
  int s, d, id;
  if (e < NE){ s = ei[e];  d = ei[NE + e]; id = e;      }   // (src,dst)
  else       { s = ei[e];  d = ei[e - NE]; id = e - NE; }   // (dst,src)
  int pos = atomicAdd(&cur[d], 1);
  nbr[pos] = s; dstA[pos] = d; eid[pos] = id;
}

// ---------------- weight pack to MFMA B-fragment order (bf16) ----------------
__global__ void k_pack(const float* __restrict__ nw1, const float* __restrict__ nw2,
                       const float* __restrict__ ew1, const float* __restrict__ ew2,
                       unsigned short* __restrict__ wp){
  int t = blockIdx.x*256 + threadIdx.x;
  if (t >= 98304) return;
  const float* src; int NO, p, base;
  if (t < 49152)      { int l = t/16384;            src = nw1 + l*16384; NO=128; p = t - l*16384;      base = t - p; }
  else if (t < 73728) { int q = t-49152; int l=q/8192; src = nw2 + l*8192; NO=64; p = q - l*8192;      base = t - p; }
  else if (t < 90112) {                              src = ew1;           NO=128; p = t - 73728;       base = 73728; }
  else                {                              src = ew2;           NO=64;  p = t - 90112;       base = 90112; }
  int f = p >> 9, r = p & 511, lane = r >> 3, i = r & 7;
  int NB = NO >> 4, kb = f / NB, nb = f - kb*NB;
  int k = kb*32 + ((lane >> 4) << 3) + i;
  int c = nb*16 + (lane & 15);
  wp[base + p] = f2bf(src[k*NO + c]);
}

// ---------------- node init: x = mean of incident edge features ----------------
__global__ void k_init(const float* __restrict__ ef, const int* __restrict__ off,
                       const int* __restrict__ eid, const float* __restrict__ dinv,
                       float* __restrict__ x, unsigned short* __restrict__ xbf){
  int n = blockIdx.x*4 + (threadIdx.x >> 6);
  int lane = threadIdx.x & 63;
  if (n >= NN) return;
  int s0 = off[n], s1 = off[n+1];
  float acc = 0.f;
  for (int s = s0; s < s1; s++) acc += ef[eid[s]*64 + lane];
  float v = acc * dinv[n];
  x[n*64 + lane] = v;
  xbf[n*64 + lane] = f2bf(v);
}

// ---------------- NodeConv MLP over directed edges + fused segmented aggregation ----------------
// wave tile = 32 rows (2 x 16 blocks). Weights from global (L2 broadcast).
// h via XOR-swizzled per-wave LDS (bf16, 8KB); m reuses the same buffer as f32; then
// wave-uniform segmented reduce over CSR-sorted dst -> atomicAdd into xsum.
__global__ __launch_bounds__(256,3) void k_conv(
    const unsigned short* __restrict__ xbf,
    const int* __restrict__ cdst, const int* __restrict__ cnbr,
    const unsigned short* __restrict__ wp, int w1off, int w2off,
    const float* __restrict__ b1, const float* __restrict__ b2,
    float* __restrict__ xsum)
{
  __shared__ char smem[32768];                 // 4 waves x 8KB
  int lane = threadIdx.x & 63, wid = threadIdx.x >> 6;
  int tile = (blockIdx.x*4 + wid) * 32;
  if (tile >= DE) return;
  char* hw = smem + wid*8192;
  int r16 = lane & 15, g = lane >> 4;
  const svec8* w1g = (const svec8*)(wp + w1off);
  const svec8* w2g = (const svec8*)(wp + w2off);

  f32x4 acc1[8][2];
  #pragma unroll
  for (int nb = 0; nb < 8; nb++){ acc1[nb][0] = (f32x4){0,0,0,0}; acc1[nb][1] = (f32x4){0,0,0,0}; }

  #pragma unroll
  for (int kb = 0; kb < 4; kb++){
    int k0 = kb*32 + g*8;
    const int* ns = (kb < 2) ? cdst : cnbr;      // cat[x_dst, x_src]
    int sa = tile + r16;       if (sa >= DE) sa = DE-1;
    int sb = tile + 16 + r16;  if (sb >= DE) sb = DE-1;
    bfrag a0 = __builtin_bit_cast(bfrag, *(const svec8*)(xbf + ns[sa]*64 + (k0 & 63)));
    bfrag a1 = __builtin_bit_cast(bfrag, *(const svec8*)(xbf + ns[sb]*64 + (k0 & 63)));
    #pragma unroll
    for (int nb = 0; nb < 8; nb++){
      bfrag b = __builtin_bit_cast(bfrag, w1g[(kb*8+nb)*64 + lane]);
      acc1[nb][0] = MFMA(a0, b, acc1[nb][0], 0, 0, 0);
      acc1[nb][1] = MFMA(a1, b, acc1[nb][1], 0, 0, 0);
    }
  }
  // h (relu) -> swizzled LDS bf16, row stride 256B, byte ^= (row&7)<<4
  #pragma unroll
  for (int nb = 0; nb < 8; nb++){
    float bias = b1[nb*16 + r16];
    #pragma unroll
    for (int rb = 0; rb < 2; rb++){
      #pragma unroll
      for (int j = 0; j < 4; j++){
        float v = acc1[nb][rb][j] + bias; v = v > 0.f ? v : 0.f;
        int row = rb*16 + g*4 + j;
        int byt = row*256 + (nb*16 + r16)*2;  byt ^= (row & 7) << 4;
        *(short*)(hw + byt) = (short)f2bf(v);
      }
    }
  }
  f32x4 acc2[4][2];
  #pragma unroll
  for (int nb = 0; nb < 4; nb++){ acc2[nb][0] = (f32x4){0,0,0,0}; acc2[nb][1] = (f32x4){0,0,0,0}; }
  #pragma unroll
  for (int kb = 0; kb < 4; kb++){
    bfrag a2[2];
    #pragma unroll
    for (int rb = 0; rb < 2; rb++){
      int row = rb*16 + r16;
      int byt = row*256 + (kb*32 + g*8)*2;  byt ^= (row & 7) << 4;
      a2[rb] = __builtin_bit_cast(bfrag, *(const svec8*)(hw + byt));
    }
    #pragma unroll
    for (int nb = 0; nb < 4; nb++){
      bfrag b = __builtin_bit_cast(bfrag, w2g[(kb*4+nb)*64 + lane]);
      acc2[nb][0] = MFMA(a2[0], b, acc2[nb][0], 0, 0, 0);
      acc2[nb][1] = MFMA(a2[1], b, acc2[nb][1], 0, 0, 0);
    }
  }
  // m (relu) -> same per-wave LDS as f32 (all h reads precede these writes in program order)
  float* mw = (float*)hw;
  #pragma unroll
  for (int nb = 0; nb < 4; nb++){
    float bias = b2[nb*16 + r16];
    #pragma unroll
    for (int rb = 0; rb < 2; rb++){
      #pragma unroll
      for (int j = 0; j < 4; j++){
        int row = rb*16 + g*4 + j;
        int col = nb*16 + r16;
        float v = acc2[nb][rb][j] + bias; v = v > 0.f ? v : 0.f;
        mw[row*64 + (col ^ ((row & 7) << 2))] = v;
      }
    }
  }
  // wave-uniform segmented reduce over CSR-sorted dst; lane = feature column
  int nv = DE - tile; if (nv > 32) nv = 32;
  float acc = 0.f;
  int dprev = __builtin_amdgcn_readfirstlane(cdst[tile]);
  for (int r = 0; r < nv; r++){
    int d = __builtin_amdgcn_readfirstlane(cdst[tile + r]);
    if (d != dprev){
      atomicAdd(&xsum[dprev*64 + lane], acc);
      acc = 0.f; dprev = d;
    }
    acc += mw[r*64 + (lane ^ ((r & 7) << 2))];
  }
  atomicAdd(&xsum[dprev*64 + lane], acc);
}

// ---------------- residual update: x += xsum * dinv ----------------
__global__ void k_finish(const float* __restrict__ xsum, const float* __restrict__ dinv,
                         float* __restrict__ x, unsigned short* __restrict__ xbf){
  int n = blockIdx.x*4 + (threadIdx.x >> 6);
  int lane = threadIdx.x & 63;
  if (n >= NN) return;
  float v = x[n*64 + lane] + xsum[n*64 + lane] * dinv[n];
  x[n*64 + lane] = v;
  xbf[n*64 + lane] = f2bf(v);
}

// ---------------- symmetric edge MLP; both directions as the two row-blocks ----------------
__global__ __launch_bounds__(256,3) void k_edge(
    const unsigned short* __restrict__ xbf, const int* __restrict__ ei,
    const unsigned short* __restrict__ wp,
    const float* __restrict__ b1, const float* __restrict__ b2,
    float* __restrict__ outp, float* __restrict__ side)
{
  __shared__ char smem[32768];
  int lane = threadIdx.x & 63, wid = threadIdx.x >> 6;
  int tile = (blockIdx.x*4 + wid) * 16;          // 16 undirected edges (NE%16==0)
  if (tile >= NE) return;
  char* hw = smem + wid*8192;
  int r16 = lane & 15, g = lane >> 4;
  const svec8* w1g = (const svec8*)(wp + 73728);
  const svec8* w2g = (const svec8*)(wp + 90112);
  int el = tile + r16;
  int sn = ei[el], dn = ei[NE + el];

  f32x4 acc1[8][2];
  #pragma unroll
  for (int nb = 0; nb < 8; nb++){ acc1[nb][0] = (f32x4){0,0,0,0}; acc1[nb][1] = (f32x4){0,0,0,0}; }

  #pragma unroll
  for (int kb = 0; kb < 4; kb++){
    int k0 = kb*32 + g*8;
    int n0 = (kb < 2) ? sn : dn;                 // dir0 = cat[x_src, x_dst]
    int n1 = (kb < 2) ? dn : sn;                 // dir1 = cat[x_dst, x_src]
    bfrag a0 = __builtin_bit_cast(bfrag, *(const svec8*)(xbf + n0*64 + (k0 & 63)));
    bfrag a1 = __builtin_bit_cast(bfrag, *(const svec8*)(xbf + n1*64 + (k0 & 63)));
    #pragma unroll
    for (int nb = 0; nb < 8; nb++){
      bfrag b = __builtin_bit_cast(bfrag, w1g[(kb*8+nb)*64 + lane]);
      acc1[nb][0] = MFMA(a0, b, acc1[nb][0], 0, 0, 0);
      acc1[nb][1] = MFMA(a1, b, acc1[nb][1], 0, 0, 0);
    }
  }
  #pragma unroll
  for (int nb = 0; nb < 8; nb++){
    float bias = b1[nb*16 + r16];
    #pragma unroll
    for (int rb = 0; rb < 2; rb++){
      #pragma unroll
      for (int j = 0; j < 4; j++){
        float v = acc1[nb][rb][j] + bias; v = v > 0.f ? v : 0.f;
        int row = rb*16 + g*4 + j;
        int byt = row*256 + (nb*16 + r16)*2;  byt ^= (row & 7) << 4;
        *(short*)(hw + byt) = (short)f2bf(v);
      }
    }
  }
  f32x4 acc2[4][2];
  #pragma unroll
  for (int nb = 0; nb < 4; nb++){ acc2[nb][0] = (f32x4){0,0,0,0}; acc2[nb][1] = (f32x4){0,0,0,0}; }
  #pragma unroll
  for (int kb = 0; kb < 4; kb++){
    bfrag a2[2];
    #pragma unroll
    for (int rb = 0; rb < 2; rb++){
      int row = rb*16 + r16;
      int byt = row*256 + (kb*32 + g*8)*2;  byt ^= (row & 7) << 4;
      a2[rb] = __builtin_bit_cast(bfrag, *(const svec8*)(hw + byt));
    }
    #pragma unroll
    for (int nb = 0; nb < 4; nb++){
      bfrag b = __builtin_bit_cast(bfrag, w2g[(kb*4+nb)*64 + lane]);
      acc2[nb][0] = MFMA(a2[0], b, acc2[nb][0], 0, 0, 0);   // e1
      acc2[nb][1] = MFMA(a2[1], b, acc2[nb][1], 0, 0, 0);   // e2
    }
  }
  float lsum = 0.f;
  #pragma unroll
  for (int nb = 0; nb < 4; nb++){
    float bias = b2[nb*16 + r16];
    #pragma unroll
    for (int j = 0; j < 4; j++){
      float v1 = acc2[nb][0][j] + bias;
      float v2 = acc2[nb][1][j] + bias;
      int e = tile + g*4 + j;
      outp[e*64 + nb*16 + r16] = 0.5f*(v1 + v2);
      float d = v1 - v2; lsum += d*d;
    }
  }
  for (int o2 = 32; o2 > 0; o2 >>= 1) lsum += __shfl_down(lsum, o2);
  if (lane == 0) atomicAdd(side, lsum);
}

__global__ void k_final(const float* __restrict__ side, float* __restrict__ outp){
  if (threadIdx.x == 0) outp[32000000] = side[0] * (1.0f / 32000000.0f);
}

// ---------------- launch ----------------
extern "C" void kernel_launch(void* const* d_in, const int* in_sizes, int n_in,
                              void* d_out, int out_size, void* d_ws, size_t ws_size,
                              hipStream_t stream)
{
  const float* ef  = (const float*)d_in[0];
  const int*   ei  = (const int*)  d_in[1];
  const float* nw1 = (const float*)d_in[2];
  const float* nb1 = (const float*)d_in[3];
  const float* nw2 = (const float*)d_in[4];
  const float* nb2 = (const float*)d_in[5];
  const float* ew1 = (const float*)d_in[6];
  const float* eb1 = (const float*)d_in[7];
  const float* ew2 = (const float*)d_in[8];
  const float* eb2 = (const float*)d_in[9];
  float* outp = (float*)d_out;

  char* ws = (char*)d_ws;
  size_t o = 0;
  auto alloc = [&](size_t b)->char*{ char* p = ws + o; o += (b + 255) & ~(size_t)255; return p; };
  int*   cnt  = (int*)  alloc((size_t)NN*4);
  int*   off  = (int*)  alloc((size_t)(NN+1)*4);
  int*   cur  = (int*)  alloc((size_t)NN*4);
  float* dinv = (float*)alloc((size_t)NN*4);
  int*   nbr  = (int*)  alloc((size_t)DE*4);
  int*   dstA = (int*)  alloc((size_t)DE*4);
  int*   eid  = (int*)  alloc((size_t)DE*4);
  float* x    = (float*)alloc((size_t)NN*64*4);
  unsigned short* xbf = (unsigned short*)alloc((size_t)NN*64*2);
  unsigned short* wp  = (unsigned short*)alloc((size_t)98304*2);
  float* side = (float*)alloc(256);
  float* xs0  = (float*)alloc((size_t)NN*64*4);
  float* xs1  = (float*)alloc((size_t)NN*64*4);
  float* xs2  = (float*)alloc((size_t)NN*64*4);
  float* xsum[3] = {xs0, xs1, xs2};

  hipMemsetAsync(cnt, 0, (size_t)NN*4, stream);
  hipMemsetAsync(side, 0, 4, stream);
  hipMemsetAsync(xs0, 0, (size_t)NN*64*4, stream);
  hipMemsetAsync(xs1, 0, (size_t)NN*64*4, stream);
  hipMemsetAsync(xs2, 0, (size_t)NN*64*4, stream);
  k_hist<<<(DE+255)/256, 256, 0, stream>>>(ei, cnt);
  k_scan<<<1, 1024, 0, stream>>>(cnt, off, cur, dinv);
  k_fill<<<(DE+255)/256, 256, 0, stream>>>(ei, cur, nbr, dstA, eid);
  k_pack<<<384, 256, 0, stream>>>(nw1, nw2, ew1, ew2, wp);
  k_init<<<NN/4, 256, 0, stream>>>(ef, off, eid, dinv, x, xbf);
  for (int l = 0; l < 3; l++){
    k_conv<<<DE/128 + 1, 256, 0, stream>>>(xbf, dstA, nbr, wp,
                                           l*16384, 49152 + l*8192,
                                           nb1 + l*128, nb2 + l*64, xsum[l]);
    k_finish<<<NN/4 + 1, 256, 0, stream>>>(xsum[l], dinv, x, xbf);
  }
  k_edge<<<NE/64 + 1, 256, 0, stream>>>(xbf, ei, wp, eb1, eb2, outp, side);
  k_final<<<1, 64, 0, stream>>>(side, outp);
}

// Round 3
// 1121.831 us; speedup vs baseline: 1.2683x; 1.2683x over previous
//
#include <hip/hip_runtime.h>

// GlobalEdgeGnn on MI355X (gfx950) — round 2.
// Change vs round 1 (single structural edit for attribution):
//  - k_edge: REMOVED the single-address atomicAdd(side) (31250 same-address device atomics
//    ~= 32 cyc each serialized = the whole 422us). Per-block partials + k_final reduction.
//  - k_edge: dedup'd A-gathers: e1/e2 share the same 4 node-row chunks (8 loads -> 4).
//  - conv/init untouched (their true counters will surface in top-5 next round).

#define NN 50000
#define NE 500000
#define DE 1000000   // 2E directed
#define DD 64
#define HH 128
#define NEB 7813     // k_edge grid blocks = NE/64 + 1

typedef __attribute__((ext_vector_type(8))) __bf16 bfrag;
typedef __attribute__((ext_vector_type(8))) short  svec8;
typedef __attribute__((ext_vector_type(4))) float  f32x4;

__device__ __forceinline__ unsigned short f2bf(float f){
  unsigned u = __builtin_bit_cast(unsigned, f);
  u += 0x7fffu + ((u >> 16) & 1u);          // RNE
  return (unsigned short)(u >> 16);
}
__device__ __forceinline__ float bf2f(unsigned short s){
  return __builtin_bit_cast(float, ((unsigned)s) << 16);
}
#define MFMA __builtin_amdgcn_mfma_f32_16x16x32_bf16

// ---------------- CSR build ----------------
__global__ void k_hist(const int* __restrict__ ei, int* __restrict__ cnt){
  int e = blockIdx.x*256 + threadIdx.x;
  if (e >= DE) return;
  int dst = (e < NE) ? ei[NE + e] : ei[e - NE];   // bi_dst
  atomicAdd(&cnt[dst], 1);
}

// two-pass scan: 1024 threads, 49 nodes/thread; shuffle scan of per-thread sums.
__global__ void k_scan(const int* __restrict__ cnt, int* __restrict__ off,
                       int* __restrict__ cur, float* __restrict__ dinv){
  __shared__ int wsum[16];
  const int CH = 49;                         // 1024*49 >= 50000
  int tid = threadIdx.x;
  int base = tid * CH;
  int s = 0;
  for (int i = 0; i < CH; i++){
    int idx = base + i;
    if (idx < NN) s += cnt[idx];
  }
  int lane = tid & 63, w = tid >> 6;
  int inc = s;
  for (int o2 = 1; o2 < 64; o2 <<= 1){
    int t = __shfl_up(inc, o2);
    if (lane >= o2) inc += t;
  }
  if (lane == 63) wsum[w] = inc;
  __syncthreads();
  if (tid < 16){
    int v = wsum[tid], p = v;
    for (int o2 = 1; o2 < 16; o2 <<= 1){
      int t = __shfl_up(p, o2, 16);
      if (tid >= o2) p += t;
    }
    wsum[tid] = p - v;                       // exclusive wave offsets
  }
  __syncthreads();
  int pre = wsum[w] + inc - s;               // exclusive prefix for this thread
  for (int i = 0; i < CH; i++){
    int idx = base + i;
    if (idx < NN){
      int v = cnt[idx];
      off[idx] = pre; cur[idx] = pre;
      dinv[idx] = 1.0f / (float)(v > 1 ? v : 1);
      pre += v;
    }
  }
  if (tid == 0) off[NN] = DE;
}

__global__ void k_fill(const int* __restrict__ ei, int* __restrict__ cur,
                       int* __restrict__ nbr, int* __restrict__ dstA, int* __restrict__ eid){
  int e = blockIdx.x*256 + threadIdx.x;
  if (e >= DE) return;
  int s, d, id;
  if (e < NE){ s = ei[e];  d = ei[NE + e]; id = e;      }   // (src,dst)
  else       { s = ei[e];  d = ei[e - NE]; id = e - NE; }   // (dst,src)
  int pos = atomicAdd(&cur[d], 1);
  nbr[pos] = s; dstA[pos] = d; eid[pos] = id;
}

// ---------------- weight pack to MFMA B-fragment order (bf16) ----------------
__global__ void k_pack(const float* __restrict__ nw1, const float* __restrict__ nw2,
                       const float* __restrict__ ew1, const float* __restrict__ ew2,
                       unsigned short* __restrict__ wp){
  int t = blockIdx.x*256 + threadIdx.x;
  if (t >= 98304) return;
  const float* src; int NO, p, base;
  if (t < 49152)      { int l = t/16384;            src = nw1 + l*16384; NO=128; p = t - l*16384;      base = t - p; }
  else if (t < 73728) { int q = t-49152; int l=q/8192; src = nw2 + l*8192; NO=64; p = q - l*8192;      base = t - p; }
  else if (t < 90112) {                              src = ew1;           NO=128; p = t - 73728;       base = 73728; }
  else                {                              src = ew2;           NO=64;  p = t - 90112;       base = 90112; }
  int f = p >> 9, r = p & 511, lane = r >> 3, i = r & 7;
  int NB = NO >> 4, kb = f / NB, nb = f - kb*NB;
  int k = kb*32 + ((lane >> 4) << 3) + i;
  int c = nb*16 + (lane & 15);
  wp[base + p] = f2bf(src[k*NO + c]);
}

// ---------------- node init: x = mean of incident edge features ----------------
__global__ void k_init(const float* __restrict__ ef, const int* __restrict__ off,
                       const int* __restrict__ eid, const float* __restrict__ dinv,
                       float* __restrict__ x, unsigned short* __restrict__ xbf){
  int n = blockIdx.x*4 + (threadIdx.x >> 6);
  int lane = threadIdx.x & 63;
  if (n >= NN) return;
  int s0 = off[n], s1 = off[n+1];
  float acc = 0.f;
  for (int s = s0; s < s1; s++) acc += ef[eid[s]*64 + lane];
  float v = acc * dinv[n];
  x[n*64 + lane] = v;
  xbf[n*64 + lane] = f2bf(v);
}

// ---------------- NodeConv MLP over directed edges + fused segmented aggregation ----------------
__global__ __launch_bounds__(256,3) void k_conv(
    const unsigned short* __restrict__ xbf,
    const int* __restrict__ cdst, const int* __restrict__ cnbr,
    const unsigned short* __restrict__ wp, int w1off, int w2off,
    const float* __restrict__ b1, const float* __restrict__ b2,
    float* __restrict__ xsum)
{
  __shared__ char smem[32768];                 // 4 waves x 8KB
  int lane = threadIdx.x & 63, wid = threadIdx.x >> 6;
  int tile = (blockIdx.x*4 + wid) * 32;
  if (tile >= DE) return;
  char* hw = smem + wid*8192;
  int r16 = lane & 15, g = lane >> 4;
  const svec8* w1g = (const svec8*)(wp + w1off);
  const svec8* w2g = (const svec8*)(wp + w2off);

  f32x4 acc1[8][2];
  #pragma unroll
  for (int nb = 0; nb < 8; nb++){ acc1[nb][0] = (f32x4){0,0,0,0}; acc1[nb][1] = (f32x4){0,0,0,0}; }

  #pragma unroll
  for (int kb = 0; kb < 4; kb++){
    int k0 = kb*32 + g*8;
    const int* ns = (kb < 2) ? cdst : cnbr;      // cat[x_dst, x_src]
    int sa = tile + r16;       if (sa >= DE) sa = DE-1;
    int sb = tile + 16 + r16;  if (sb >= DE) sb = DE-1;
    bfrag a0 = __builtin_bit_cast(bfrag, *(const svec8*)(xbf + ns[sa]*64 + (k0 & 63)));
    bfrag a1 = __builtin_bit_cast(bfrag, *(const svec8*)(xbf + ns[sb]*64 + (k0 & 63)));
    #pragma unroll
    for (int nb = 0; nb < 8; nb++){
      bfrag b = __builtin_bit_cast(bfrag, w1g[(kb*8+nb)*64 + lane]);
      acc1[nb][0] = MFMA(a0, b, acc1[nb][0], 0, 0, 0);
      acc1[nb][1] = MFMA(a1, b, acc1[nb][1], 0, 0, 0);
    }
  }
  // h (relu) -> swizzled LDS bf16, row stride 256B, byte ^= (row&7)<<4
  #pragma unroll
  for (int nb = 0; nb < 8; nb++){
    float bias = b1[nb*16 + r16];
    #pragma unroll
    for (int rb = 0; rb < 2; rb++){
      #pragma unroll
      for (int j = 0; j < 4; j++){
        float v = acc1[nb][rb][j] + bias; v = v > 0.f ? v : 0.f;
        int row = rb*16 + g*4 + j;
        int byt = row*256 + (nb*16 + r16)*2;  byt ^= (row & 7) << 4;
        *(short*)(hw + byt) = (short)f2bf(v);
      }
    }
  }
  f32x4 acc2[4][2];
  #pragma unroll
  for (int nb = 0; nb < 4; nb++){ acc2[nb][0] = (f32x4){0,0,0,0}; acc2[nb][1] = (f32x4){0,0,0,0}; }
  #pragma unroll
  for (int kb = 0; kb < 4; kb++){
    bfrag a2[2];
    #pragma unroll
    for (int rb = 0; rb < 2; rb++){
      int row = rb*16 + r16;
      int byt = row*256 + (kb*32 + g*8)*2;  byt ^= (row & 7) << 4;
      a2[rb] = __builtin_bit_cast(bfrag, *(const svec8*)(hw + byt));
    }
    #pragma unroll
    for (int nb = 0; nb < 4; nb++){
      bfrag b = __builtin_bit_cast(bfrag, w2g[(kb*4+nb)*64 + lane]);
      acc2[nb][0] = MFMA(a2[0], b, acc2[nb][0], 0, 0, 0);
      acc2[nb][1] = MFMA(a2[1], b, acc2[nb][1], 0, 0, 0);
    }
  }
  // m (relu) -> same per-wave LDS as f32 (all h reads precede these writes in program order)
  float* mw = (float*)hw;
  #pragma unroll
  for (int nb = 0; nb < 4; nb++){
    float bias = b2[nb*16 + r16];
    #pragma unroll
    for (int rb = 0; rb < 2; rb++){
      #pragma unroll
      for (int j = 0; j < 4; j++){
        int row = rb*16 + g*4 + j;
        int col = nb*16 + r16;
        float v = acc2[nb][rb][j] + bias; v = v > 0.f ? v : 0.f;
        mw[row*64 + (col ^ ((row & 7) << 2))] = v;
      }
    }
  }
  // wave-uniform segmented reduce over CSR-sorted dst; lane = feature column
  int nv = DE - tile; if (nv > 32) nv = 32;
  float acc = 0.f;
  int dprev = __builtin_amdgcn_readfirstlane(cdst[tile]);
  for (int r = 0; r < nv; r++){
    int d = __builtin_amdgcn_readfirstlane(cdst[tile + r]);
    if (d != dprev){
      atomicAdd(&xsum[dprev*64 + lane], acc);
      acc = 0.f; dprev = d;
    }
    acc += mw[r*64 + (lane ^ ((r & 7) << 2))];
  }
  atomicAdd(&xsum[dprev*64 + lane], acc);
}

// ---------------- residual update: x += xsum * dinv ----------------
__global__ void k_finish(const float* __restrict__ xsum, const float* __restrict__ dinv,
                         float* __restrict__ x, unsigned short* __restrict__ xbf){
  int n = blockIdx.x*4 + (threadIdx.x >> 6);
  int lane = threadIdx.x & 63;
  if (n >= NN) return;
  float v = x[n*64 + lane] + xsum[n*64 + lane] * dinv[n];
  x[n*64 + lane] = v;
  xbf[n*64 + lane] = f2bf(v);
}

// ---------------- symmetric edge MLP; both directions as the two row-blocks ----------------
// No same-address atomics: per-block loss partial written to part[], reduced by k_final.
__global__ __launch_bounds__(256,3) void k_edge(
    const unsigned short* __restrict__ xbf, const int* __restrict__ ei,
    const unsigned short* __restrict__ wp,
    const float* __restrict__ b1, const float* __restrict__ b2,
    float* __restrict__ outp, float* __restrict__ part)
{
  __shared__ char smem[32768];
  __shared__ float wred[4];
  int lane = threadIdx.x & 63, wid = threadIdx.x >> 6;
  int tile = (blockIdx.x*4 + wid) * 16;          // 16 undirected edges
  bool valid = tile < NE;
  int tl = valid ? tile : 0;
  char* hw = smem + wid*8192;
  int r16 = lane & 15, g = lane >> 4;
  const svec8* w1g = (const svec8*)(wp + 73728);
  const svec8* w2g = (const svec8*)(wp + 90112);
  int el = tl + r16;
  int sn = ei[el], dn = ei[NE + el];

  // dedup'd gathers: e1 A-seq = {sA,sB,dA,dB}, e2 A-seq = {dA,dB,sA,sB}
  bfrag sA = __builtin_bit_cast(bfrag, *(const svec8*)(xbf + sn*64 + g*8));
  bfrag sB = __builtin_bit_cast(bfrag, *(const svec8*)(xbf + sn*64 + 32 + g*8));
  bfrag dA = __builtin_bit_cast(bfrag, *(const svec8*)(xbf + dn*64 + g*8));
  bfrag dB = __builtin_bit_cast(bfrag, *(const svec8*)(xbf + dn*64 + 32 + g*8));
  bfrag a0f[4] = {sA, sB, dA, dB};
  bfrag a1f[4] = {dA, dB, sA, sB};

  f32x4 acc1[8][2];
  #pragma unroll
  for (int nb = 0; nb < 8; nb++){ acc1[nb][0] = (f32x4){0,0,0,0}; acc1[nb][1] = (f32x4){0,0,0,0}; }

  #pragma unroll
  for (int kb = 0; kb < 4; kb++){
    #pragma unroll
    for (int nb = 0; nb < 8; nb++){
      bfrag b = __builtin_bit_cast(bfrag, w1g[(kb*8+nb)*64 + lane]);
      acc1[nb][0] = MFMA(a0f[kb], b, acc1[nb][0], 0, 0, 0);
      acc1[nb][1] = MFMA(a1f[kb], b, acc1[nb][1], 0, 0, 0);
    }
  }
  #pragma unroll
  for (int nb = 0; nb < 8; nb++){
    float bias = b1[nb*16 + r16];
    #pragma unroll
    for (int rb = 0; rb < 2; rb++){
      #pragma unroll
      for (int j = 0; j < 4; j++){
        float v = acc1[nb][rb][j] + bias; v = v > 0.f ? v : 0.f;
        int row = rb*16 + g*4 + j;
        int byt = row*256 + (nb*16 + r16)*2;  byt ^= (row & 7) << 4;
        *(short*)(hw + byt) = (short)f2bf(v);
      }
    }
  }
  f32x4 acc2[4][2];
  #pragma unroll
  for (int nb = 0; nb < 4; nb++){ acc2[nb][0] = (f32x4){0,0,0,0}; acc2[nb][1] = (f32x4){0,0,0,0}; }
  #pragma unroll
  for (int kb = 0; kb < 4; kb++){
    bfrag a2[2];
    #pragma unroll
    for (int rb = 0; rb < 2; rb++){
      int row = rb*16 + r16;
      int byt = row*256 + (kb*32 + g*8)*2;  byt ^= (row & 7) << 4;
      a2[rb] = __builtin_bit_cast(bfrag, *(const svec8*)(hw + byt));
    }
    #pragma unroll
    for (int nb = 0; nb < 4; nb++){
      bfrag b = __builtin_bit_cast(bfrag, w2g[(kb*4+nb)*64 + lane]);
      acc2[nb][0] = MFMA(a2[0], b, acc2[nb][0], 0, 0, 0);   // e1
      acc2[nb][1] = MFMA(a2[1], b, acc2[nb][1], 0, 0, 0);   // e2
    }
  }
  float lsum = 0.f;
  #pragma unroll
  for (int nb = 0; nb < 4; nb++){
    float bias = b2[nb*16 + r16];
    #pragma unroll
    for (int j = 0; j < 4; j++){
      float v1 = acc2[nb][0][j] + bias;
      float v2 = acc2[nb][1][j] + bias;
      int e = tile + g*4 + j;
      if (valid) outp[e*64 + nb*16 + r16] = 0.5f*(v1 + v2);
      float d = v1 - v2; lsum += d*d;
    }
  }
  if (!valid) lsum = 0.f;
  for (int o2 = 32; o2 > 0; o2 >>= 1) lsum += __shfl_down(lsum, o2);
  if (lane == 0) wred[wid] = lsum;
  __syncthreads();
  if (threadIdx.x == 0) part[blockIdx.x] = wred[0] + wred[1] + wred[2] + wred[3];
}

// ---------------- final loss reduction over per-block partials ----------------
__global__ void k_final(const float* __restrict__ part, float* __restrict__ outp){
  __shared__ float wred[16];
  int tid = threadIdx.x;
  float s = 0.f;
  for (int i = tid; i < NEB; i += 1024) s += part[i];
  for (int o2 = 32; o2 > 0; o2 >>= 1) s += __shfl_down(s, o2);
  int lane = tid & 63, w = tid >> 6;
  if (lane == 0) wred[w] = s;
  __syncthreads();
  if (tid == 0){
    float t = 0.f;
    #pragma unroll
    for (int i = 0; i < 16; i++) t += wred[i];
    outp[32000000] = t * (1.0f / 32000000.0f);
  }
}

// ---------------- launch ----------------
extern "C" void kernel_launch(void* const* d_in, const int* in_sizes, int n_in,
                              void* d_out, int out_size, void* d_ws, size_t ws_size,
                              hipStream_t stream)
{
  const float* ef  = (const float*)d_in[0];
  const int*   ei  = (const int*)  d_in[1];
  const float* nw1 = (const float*)d_in[2];
  const float* nb1 = (const float*)d_in[3];
  const float* nw2 = (const float*)d_in[4];
  const float* nb2 = (const float*)d_in[5];
  const float* ew1 = (const float*)d_in[6];
  const float* eb1 = (const float*)d_in[7];
  const float* ew2 = (const float*)d_in[8];
  const float* eb2 = (const float*)d_in[9];
  float* outp = (float*)d_out;

  char* ws = (char*)d_ws;
  size_t o = 0;
  auto alloc = [&](size_t b)->char*{ char* p = ws + o; o += (b + 255) & ~(size_t)255; return p; };
  int*   cnt  = (int*)  alloc((size_t)NN*4);
  int*   off  = (int*)  alloc((size_t)(NN+1)*4);
  int*   cur  = (int*)  alloc((size_t)NN*4);
  float* dinv = (float*)alloc((size_t)NN*4);
  int*   nbr  = (int*)  alloc((size_t)DE*4);
  int*   dstA = (int*)  alloc((size_t)DE*4);
  int*   eid  = (int*)  alloc((size_t)DE*4);
  float* x    = (float*)alloc((size_t)NN*64*4);
  unsigned short* xbf = (unsigned short*)alloc((size_t)NN*64*2);
  unsigned short* wp  = (unsigned short*)alloc((size_t)98304*2);
  float* part = (float*)alloc((size_t)NEB*4);
  float* xs0  = (float*)alloc((size_t)NN*64*4);
  float* xs1  = (float*)alloc((size_t)NN*64*4);
  float* xs2  = (float*)alloc((size_t)NN*64*4);
  float* xsum[3] = {xs0, xs1, xs2};

  hipMemsetAsync(cnt, 0, (size_t)NN*4, stream);
  hipMemsetAsync(xs0, 0, (size_t)NN*64*4, stream);
  hipMemsetAsync(xs1, 0, (size_t)NN*64*4, stream);
  hipMemsetAsync(xs2, 0, (size_t)NN*64*4, stream);
  k_hist<<<(DE+255)/256, 256, 0, stream>>>(ei, cnt);
  k_scan<<<1, 1024, 0, stream>>>(cnt, off, cur, dinv);
  k_fill<<<(DE+255)/256, 256, 0, stream>>>(ei, cur, nbr, dstA, eid);
  k_pack<<<384, 256, 0, stream>>>(nw1, nw2, ew1, ew2, wp);
  k_init<<<NN/4, 256, 0, stream>>>(ef, off, eid, dinv, x, xbf);
  for (int l = 0; l < 3; l++){
    k_conv<<<DE/128 + 1, 256, 0, stream>>>(xbf, dstA, nbr, wp,
                                           l*16384, 49152 + l*8192,
                                           nb1 + l*128, nb2 + l*64, xsum[l]);
    k_finish<<<NN/4 + 1, 256, 0, stream>>>(xsum[l], dinv, x, xbf);
  }
  k_edge<<<NEB, 256, 0, stream>>>(xbf, ei, wp, eb1, eb2, outp, part);
  k_final<<<1, 1024, 0, stream>>>(part, outp);
}

// Round 4
// 827.113 us; speedup vs baseline: 1.7203x; 1.3563x over previous
//
#include <hip/hip_runtime.h>

// GlobalEdgeGnn on MI355X (gfx950) — round 3.
// Key change: P/Q factorization. m = MLP(cat[x_dst,x_src]) => precompute per-node
//   P = x@W1[0:64]+b1, Q = x@W1[64:128]  (k_pq, node-level MFMA, ~1.6 GFLOP vs 66)
// then per edge h = relu(P[dst]+Q[src]) built DIRECTLY in A-fragment layout in regs:
//   - GEMM1 per edge: gone (64 MFMA/wave -> 0)
//   - h LDS round-trip: gone (k_conv uses no LDS at all)
//   - segmented reduce: ballot-based segment boundaries, register partials,
//     shfl_xor cross-group reduce, ~2.6 uniform iterations (was 32 serial loads).
// Edge MLP identically: PE = x@ew1[0:64]+eb1, QE = x@ew1[64:128].

#define NN 50000
#define NE 500000
#define DE 1000000   // 2E directed
#define NEB 7813     // k_edge grid blocks

typedef __attribute__((ext_vector_type(8))) __bf16 bfrag;
typedef __attribute__((ext_vector_type(8))) short  svec8;
typedef __attribute__((ext_vector_type(4))) float  f32x4;

__device__ __forceinline__ unsigned short f2bf(float f){
  unsigned u = __builtin_bit_cast(unsigned, f);
  u += 0x7fffu + ((u >> 16) & 1u);          // RNE
  return (unsigned short)(u >> 16);
}
__device__ __forceinline__ float bf2f(unsigned short s){
  return __builtin_bit_cast(float, ((unsigned)s) << 16);
}
#define MFMA __builtin_amdgcn_mfma_f32_16x16x32_bf16

// h-fragment builder: 8 bf16 of P + 8 bf16 of Q -> relu(P+Q) as bf16 A-fragment.
__device__ __forceinline__ bfrag hbuild(const unsigned short* __restrict__ p,
                                        const unsigned short* __restrict__ q){
  svec8 pv = *(const svec8*)p;
  svec8 qv = *(const svec8*)q;
  bfrag r;
  #pragma unroll
  for (int i = 0; i < 8; i++){
    float f = bf2f((unsigned short)pv[i]) + bf2f((unsigned short)qv[i]);
    f = f > 0.f ? f : 0.f;
    r[i] = (__bf16)f;
  }
  return r;
}

// ---------------- CSR build ----------------
__global__ void k_hist(const int* __restrict__ ei, int* __restrict__ cnt){
  int e = blockIdx.x*256 + threadIdx.x;
  if (e >= DE) return;
  int dst = (e < NE) ? ei[NE + e] : ei[e - NE];   // bi_dst
  atomicAdd(&cnt[dst], 1);
}

__global__ void k_scan(const int* __restrict__ cnt, int* __restrict__ off,
                       int* __restrict__ cur, float* __restrict__ dinv){
  __shared__ int wsum[16];
  const int CH = 49;
  int tid = threadIdx.x;
  int base = tid * CH;
  int s = 0;
  for (int i = 0; i < CH; i++){
    int idx = base + i;
    if (idx < NN) s += cnt[idx];
  }
  int lane = tid & 63, w = tid >> 6;
  int inc = s;
  for (int o2 = 1; o2 < 64; o2 <<= 1){
    int t = __shfl_up(inc, o2);
    if (lane >= o2) inc += t;
  }
  if (lane == 63) wsum[w] = inc;
  __syncthreads();
  if (tid < 16){
    int v = wsum[tid], p = v;
    for (int o2 = 1; o2 < 16; o2 <<= 1){
      int t = __shfl_up(p, o2, 16);
      if (tid >= o2) p += t;
    }
    wsum[tid] = p - v;
  }
  __syncthreads();
  int pre = wsum[w] + inc - s;
  for (int i = 0; i < CH; i++){
    int idx = base + i;
    if (idx < NN){
      int v = cnt[idx];
      off[idx] = pre; cur[idx] = pre;
      dinv[idx] = 1.0f / (float)(v > 1 ? v : 1);
      pre += v;
    }
  }
  if (tid == 0) off[NN] = DE;
}

__global__ void k_fill(const int* __restrict__ ei, int* __restrict__ cur,
                       int* __restrict__ nbr, int* __restrict__ dstA, int* __restrict__ eid){
  int e = blockIdx.x*256 + threadIdx.x;
  if (e >= DE) return;
  int s, d, id;
  if (e < NE){ s = ei[e];  d = ei[NE + e]; id = e;      }
  else       { s = ei[e];  d = ei[e - NE]; id = e - NE; }
  int pos = atomicAdd(&cur[d], 1);
  nbr[pos] = s; dstA[pos] = d; eid[pos] = id;
}

// ---------------- weight pack to MFMA B-fragment order (bf16) ----------------
__global__ void k_pack(const float* __restrict__ nw1, const float* __restrict__ nw2,
                       const float* __restrict__ ew1, const float* __restrict__ ew2,
                       unsigned short* __restrict__ wp){
  int t = blockIdx.x*256 + threadIdx.x;
  if (t >= 98304) return;
  const float* src; int NO, p, base;
  if (t < 49152)      { int l = t/16384;            src = nw1 + l*16384; NO=128; p = t - l*16384;      base = t - p; }
  else if (t < 73728) { int q = t-49152; int l=q/8192; src = nw2 + l*8192; NO=64; p = q - l*8192;      base = t - p; }
  else if (t < 90112) {                              src = ew1;           NO=128; p = t - 73728;       base = 73728; }
  else                {                              src = ew2;           NO=64;  p = t - 90112;       base = 90112; }
  int f = p >> 9, r = p & 511, lane = r >> 3, i = r & 7;
  int NB = NO >> 4, kb = f / NB, nb = f - kb*NB;
  int k = kb*32 + ((lane >> 4) << 3) + i;
  int c = nb*16 + (lane & 15);
  wp[base + p] = f2bf(src[k*NO + c]);
}

// ---------------- node init: x = mean of incident edge features ----------------
__global__ void k_init(const float* __restrict__ ef, const int* __restrict__ off,
                       const int* __restrict__ eid, const float* __restrict__ dinv,
                       float* __restrict__ x, unsigned short* __restrict__ xbf){
  int n = blockIdx.x*4 + (threadIdx.x >> 6);
  int lane = threadIdx.x & 63;
  if (n >= NN) return;
  int s0 = off[n], s1 = off[n+1];
  float acc = 0.f;
  for (int s = s0; s < s1; s++) acc += ef[eid[s]*64 + lane];
  float v = acc * dinv[n];
  x[n*64 + lane] = v;
  xbf[n*64 + lane] = f2bf(v);
}

// ---------------- P/Q producer: node-level GEMM [NN,64]@[64,128] ----------------
// P = x @ W1[0:64] (+bias), uses packed frags kb=0,1 of the [128,128] pack.
// Q = x @ W1[64:128],       uses packed frags kb=2,3.
__global__ __launch_bounds__(256,2) void k_pq(
    const unsigned short* __restrict__ xbf,
    const unsigned short* __restrict__ wp, int w1off,
    const float* __restrict__ bias,
    unsigned short* __restrict__ pb, unsigned short* __restrict__ qb)
{
  int lane = threadIdx.x & 63, wid = threadIdx.x >> 6;
  int tile = (blockIdx.x*4 + wid) * 32;
  if (tile >= NN) return;
  int r16 = lane & 15, g = lane >> 4;
  const svec8* w1g = (const svec8*)(wp + w1off);
  bfrag a[2][2];
  #pragma unroll
  for (int rb = 0; rb < 2; rb++){
    int n = tile + rb*16 + r16; if (n >= NN) n = NN-1;
    #pragma unroll
    for (int kb = 0; kb < 2; kb++)
      a[rb][kb] = __builtin_bit_cast(bfrag, *(const svec8*)(xbf + n*64 + kb*32 + g*8));
  }
  for (int ph = 0; ph < 2; ph++){
    f32x4 acc[8][2];
    #pragma unroll
    for (int nb = 0; nb < 8; nb++){ acc[nb][0] = (f32x4){0,0,0,0}; acc[nb][1] = (f32x4){0,0,0,0}; }
    #pragma unroll
    for (int kb = 0; kb < 2; kb++){
      #pragma unroll
      for (int nb = 0; nb < 8; nb++){
        bfrag b = __builtin_bit_cast(bfrag, w1g[((ph*2+kb)*8+nb)*64 + lane]);
        acc[nb][0] = MFMA(a[0][kb], b, acc[nb][0], 0, 0, 0);
        acc[nb][1] = MFMA(a[1][kb], b, acc[nb][1], 0, 0, 0);
      }
    }
    unsigned short* ob = ph ? qb : pb;
    #pragma unroll
    for (int nb = 0; nb < 8; nb++){
      float bv = (ph == 0) ? bias[nb*16 + r16] : 0.f;
      #pragma unroll
      for (int rb = 0; rb < 2; rb++){
        #pragma unroll
        for (int j = 0; j < 4; j++){
          int n = tile + rb*16 + g*4 + j;
          if (n < NN) ob[n*128 + nb*16 + r16] = f2bf(acc[nb][rb][j] + bv);
        }
      }
    }
  }
}

// ---------------- NodeConv: h=relu(P[dst]+Q[src]) in regs -> GEMM2 -> seg-reduce ----------------
__global__ __launch_bounds__(256,4) void k_conv(
    const unsigned short* __restrict__ pb, const unsigned short* __restrict__ qb,
    const int* __restrict__ cdst, const int* __restrict__ cnbr,
    const unsigned short* __restrict__ wp, int w2off,
    const float* __restrict__ b2, float* __restrict__ xsum)
{
  int lane = threadIdx.x & 63, wid = threadIdx.x >> 6;
  int tile = (blockIdx.x*4 + wid) * 32;
  if (tile >= DE) return;                       // no LDS/barrier in this kernel
  int r16 = lane & 15, g = lane >> 4;
  int dr = cdst[tile + (lane & 31)];            // per-row dst for segment detection
  int d0 = cdst[tile + r16],      d1 = cdst[tile + 16 + r16];
  int s0 = cnbr[tile + r16],      s1 = cnbr[tile + 16 + r16];
  const svec8* w2g = (const svec8*)(wp + w2off);

  f32x4 acc[4][2];
  #pragma unroll
  for (int nb = 0; nb < 4; nb++){ acc[nb][0] = (f32x4){0,0,0,0}; acc[nb][1] = (f32x4){0,0,0,0}; }

  #pragma unroll
  for (int kb = 0; kb < 4; kb++){
    int off = kb*32 + g*8;
    bfrag h0 = hbuild(pb + d0*128 + off, qb + s0*128 + off);
    bfrag h1 = hbuild(pb + d1*128 + off, qb + s1*128 + off);
    #pragma unroll
    for (int nb = 0; nb < 4; nb++){
      bfrag b = __builtin_bit_cast(bfrag, w2g[(kb*4+nb)*64 + lane]);
      acc[nb][0] = MFMA(h0, b, acc[nb][0], 0, 0, 0);
      acc[nb][1] = MFMA(h1, b, acc[nb][1], 0, 0, 0);
    }
  }
  // m = relu(acc + b2), kept in registers (static indexing only)
  float m[4][2][4];
  #pragma unroll
  for (int nb = 0; nb < 4; nb++){
    float bv = b2[nb*16 + r16];
    #pragma unroll
    for (int rb = 0; rb < 2; rb++){
      #pragma unroll
      for (int j = 0; j < 4; j++){
        float v = acc[nb][rb][j] + bv;
        m[nb][rb][j] = v > 0.f ? v : 0.f;
      }
    }
  }
  // ballot-based segmented reduce over CSR-sorted dst (DE%32==0 -> full tiles)
  int prev = __shfl_up(dr, 1);
  bool flag = (lane < 32) && (lane == 0 || dr != prev);
  unsigned long long mask = __ballot(flag);
  while (mask){
    int s = (int)__builtin_ctzll(mask);
    mask &= mask - 1;
    int e = mask ? (int)__builtin_ctzll(mask) : 32;
    int dseg = __shfl(dr, s);
    float p0 = 0.f, p1 = 0.f, p2 = 0.f, p3 = 0.f;
    #pragma unroll
    for (int rb = 0; rb < 2; rb++){
      #pragma unroll
      for (int j = 0; j < 4; j++){
        int row = rb*16 + g*4 + j;
        if ((unsigned)(row - s) < (unsigned)(e - s)){
          p0 += m[0][rb][j]; p1 += m[1][rb][j]; p2 += m[2][rb][j]; p3 += m[3][rb][j];
        }
      }
    }
    p0 += __shfl_xor(p0, 16); p0 += __shfl_xor(p0, 32);
    p1 += __shfl_xor(p1, 16); p1 += __shfl_xor(p1, 32);
    p2 += __shfl_xor(p2, 16); p2 += __shfl_xor(p2, 32);
    p3 += __shfl_xor(p3, 16); p3 += __shfl_xor(p3, 32);
    if (g == 0){
      atomicAdd(&xsum[dseg*64 +      r16], p0);
      atomicAdd(&xsum[dseg*64 + 16 + r16], p1);
      atomicAdd(&xsum[dseg*64 + 32 + r16], p2);
      atomicAdd(&xsum[dseg*64 + 48 + r16], p3);
    }
  }
}

// ---------------- residual update: x += xsum * dinv ----------------
__global__ void k_finish(const float* __restrict__ xsum, const float* __restrict__ dinv,
                         float* __restrict__ x, unsigned short* __restrict__ xbf){
  int n = blockIdx.x*4 + (threadIdx.x >> 6);
  int lane = threadIdx.x & 63;
  if (n >= NN) return;
  float v = x[n*64 + lane] + xsum[n*64 + lane] * dinv[n];
  x[n*64 + lane] = v;
  xbf[n*64 + lane] = f2bf(v);
}

// ---------------- symmetric edge MLP via PE/QE ----------------
__global__ __launch_bounds__(256,4) void k_edge(
    const unsigned short* __restrict__ pe, const unsigned short* __restrict__ qe,
    const int* __restrict__ ei,
    const unsigned short* __restrict__ wp,
    const float* __restrict__ b2,
    float* __restrict__ outp, float* __restrict__ part)
{
  __shared__ float wred[4];
  int lane = threadIdx.x & 63, wid = threadIdx.x >> 6;
  int tile = (blockIdx.x*4 + wid) * 16;          // 16 undirected edges
  bool valid = tile < NE;
  int tl = valid ? tile : 0;
  int r16 = lane & 15, g = lane >> 4;
  const svec8* w2g = (const svec8*)(wp + 90112);
  int el = tl + r16;
  int sn = ei[el], dn = ei[NE + el];

  f32x4 acc[4][2];
  #pragma unroll
  for (int nb = 0; nb < 4; nb++){ acc[nb][0] = (f32x4){0,0,0,0}; acc[nb][1] = (f32x4){0,0,0,0}; }

  #pragma unroll
  for (int kb = 0; kb < 4; kb++){
    int off = kb*32 + g*8;
    bfrag h0 = hbuild(pe + sn*128 + off, qe + dn*128 + off);   // e1 = emlp(x_src, x_dst)
    bfrag h1 = hbuild(pe + dn*128 + off, qe + sn*128 + off);   // e2 = emlp(x_dst, x_src)
    #pragma unroll
    for (int nb = 0; nb < 4; nb++){
      bfrag b = __builtin_bit_cast(bfrag, w2g[(kb*4+nb)*64 + lane]);
      acc[nb][0] = MFMA(h0, b, acc[nb][0], 0, 0, 0);
      acc[nb][1] = MFMA(h1, b, acc[nb][1], 0, 0, 0);
    }
  }
  float lsum = 0.f;
  #pragma unroll
  for (int nb = 0; nb < 4; nb++){
    float bv = b2[nb*16 + r16];
    #pragma unroll
    for (int j = 0; j < 4; j++){
      float v1 = acc[nb][0][j] + bv;
      float v2 = acc[nb][1][j] + bv;
      int e = tile + g*4 + j;
      if (valid) outp[e*64 + nb*16 + r16] = 0.5f*(v1 + v2);
      float d = v1 - v2; lsum += d*d;
    }
  }
  if (!valid) lsum = 0.f;
  for (int o2 = 32; o2 > 0; o2 >>= 1) lsum += __shfl_down(lsum, o2);
  if (lane == 0) wred[wid] = lsum;
  __syncthreads();
  if (threadIdx.x == 0) part[blockIdx.x] = wred[0] + wred[1] + wred[2] + wred[3];
}

// ---------------- final loss reduction ----------------
__global__ void k_final(const float* __restrict__ part, float* __restrict__ outp){
  __shared__ float wred[16];
  int tid = threadIdx.x;
  float s = 0.f;
  for (int i = tid; i < NEB; i += 1024) s += part[i];
  for (int o2 = 32; o2 > 0; o2 >>= 1) s += __shfl_down(s, o2);
  int lane = tid & 63, w = tid >> 6;
  if (lane == 0) wred[w] = s;
  __syncthreads();
  if (tid == 0){
    float t = 0.f;
    #pragma unroll
    for (int i = 0; i < 16; i++) t += wred[i];
    outp[32000000] = t * (1.0f / 32000000.0f);
  }
}

// ---------------- launch ----------------
extern "C" void kernel_launch(void* const* d_in, const int* in_sizes, int n_in,
                              void* d_out, int out_size, void* d_ws, size_t ws_size,
                              hipStream_t stream)
{
  const float* ef  = (const float*)d_in[0];
  const int*   ei  = (const int*)  d_in[1];
  const float* nw1 = (const float*)d_in[2];
  const float* nb1 = (const float*)d_in[3];
  const float* nw2 = (const float*)d_in[4];
  const float* nb2 = (const float*)d_in[5];
  const float* ew1 = (const float*)d_in[6];
  const float* eb1 = (const float*)d_in[7];
  const float* ew2 = (const float*)d_in[8];
  const float* eb2 = (const float*)d_in[9];
  float* outp = (float*)d_out;

  char* ws = (char*)d_ws;
  size_t o = 0;
  auto alloc = [&](size_t b)->char*{ char* p = ws + o; o += (b + 255) & ~(size_t)255; return p; };
  int*   cnt  = (int*)  alloc((size_t)NN*4);
  int*   off  = (int*)  alloc((size_t)(NN+1)*4);
  int*   cur  = (int*)  alloc((size_t)NN*4);
  float* dinv = (float*)alloc((size_t)NN*4);
  int*   nbr  = (int*)  alloc((size_t)DE*4);
  int*   dstA = (int*)  alloc((size_t)DE*4);
  int*   eid  = (int*)  alloc((size_t)DE*4);
  float* x    = (float*)alloc((size_t)NN*64*4);
  unsigned short* xbf = (unsigned short*)alloc((size_t)NN*64*2);
  unsigned short* wp  = (unsigned short*)alloc((size_t)98304*2);
  float* part = (float*)alloc((size_t)NEB*4);
  unsigned short* pbuf = (unsigned short*)alloc((size_t)NN*128*2);
  unsigned short* qbuf = (unsigned short*)alloc((size_t)NN*128*2);
  float* xs0  = (float*)alloc((size_t)NN*64*4);
  float* xs1  = (float*)alloc((size_t)NN*64*4);
  float* xs2  = (float*)alloc((size_t)NN*64*4);
  float* xsum[3] = {xs0, xs1, xs2};

  hipMemsetAsync(cnt, 0, (size_t)NN*4, stream);
  hipMemsetAsync(xs0, 0, (size_t)NN*64*4, stream);
  hipMemsetAsync(xs1, 0, (size_t)NN*64*4, stream);
  hipMemsetAsync(xs2, 0, (size_t)NN*64*4, stream);
  k_hist<<<(DE+255)/256, 256, 0, stream>>>(ei, cnt);
  k_scan<<<1, 1024, 0, stream>>>(cnt, off, cur, dinv);
  k_fill<<<(DE+255)/256, 256, 0, stream>>>(ei, cur, nbr, dstA, eid);
  k_pack<<<384, 256, 0, stream>>>(nw1, nw2, ew1, ew2, wp);
  k_init<<<NN/4, 256, 0, stream>>>(ef, off, eid, dinv, x, xbf);
  for (int l = 0; l < 3; l++){
    k_pq<<<391, 256, 0, stream>>>(xbf, wp, l*16384, nb1 + l*128, pbuf, qbuf);
    k_conv<<<DE/128 + 1, 256, 0, stream>>>(pbuf, qbuf, dstA, nbr, wp,
                                           49152 + l*8192, nb2 + l*64, xsum[l]);
    k_finish<<<NN/4 + 1, 256, 0, stream>>>(xsum[l], dinv, x, xbf);
  }
  k_pq<<<391, 256, 0, stream>>>(xbf, wp, 73728, eb1, pbuf, qbuf);
  k_edge<<<NEB, 256, 0, stream>>>(pbuf, qbuf, ei, wp, eb2, outp, part);
  k_final<<<1, 1024, 0, stream>>>(part, outp);
}

// Round 6
// 700.057 us; speedup vs baseline: 2.0325x; 1.1815x over previous
//
#include <hip/hip_runtime.h>

// GlobalEdgeGnn on MI355X (gfx950) — round 5.
// Round 4 crashed: k_scan rewrite dropped the running carry (carry_s = wsum[15]+inc
// instead of carry + wsum[15] + inc) -> wrong CSR offsets -> holes in eid/dstA kept
// the 0xAA workspace poison -> k_init read ef at e=0xAAAAAAAA -> HSA memory fault.
// This round: the one-line carry fix. Everything else identical to round 4.

#define NN 50000
#define NE 500000
#define DE 1000000   // 2E directed
#define NEB 7813     // k_edge / k_init grid blocks

typedef __attribute__((ext_vector_type(8))) __bf16 bfrag;
typedef __attribute__((ext_vector_type(8))) short  svec8;
typedef __attribute__((ext_vector_type(4))) float  f32x4;

__device__ __forceinline__ unsigned short f2bf(float f){
  unsigned u = __builtin_bit_cast(unsigned, f);
  u += 0x7fffu + ((u >> 16) & 1u);          // RNE
  return (unsigned short)(u >> 16);
}
__device__ __forceinline__ float bf2f(unsigned short s){
  return __builtin_bit_cast(float, ((unsigned)s) << 16);
}
#define MFMA __builtin_amdgcn_mfma_f32_16x16x32_bf16

// h-fragment builder: 8 bf16 of P + 8 bf16 of Q -> relu(P+Q) as bf16 A-fragment.
__device__ __forceinline__ bfrag hbuild(const unsigned short* __restrict__ p,
                                        const unsigned short* __restrict__ q){
  svec8 pv = *(const svec8*)p;
  svec8 qv = *(const svec8*)q;
  bfrag r;
  #pragma unroll
  for (int i = 0; i < 8; i++){
    float f = bf2f((unsigned short)pv[i]) + bf2f((unsigned short)qv[i]);
    f = f > 0.f ? f : 0.f;
    r[i] = (__bf16)f;
  }
  return r;
}

// ---------------- CSR build ----------------
__global__ void k_hist(const int* __restrict__ ei, int* __restrict__ cnt){
  int e = blockIdx.x*256 + threadIdx.x;
  if (e >= DE) return;
  int dst = (e < NE) ? ei[NE + e] : ei[e - NE];   // bi_dst
  atomicAdd(&cnt[dst], 1);
}

// coalesced rounds: 1024 elements/round, shuffle scan + wave-offset scan + carry.
__global__ void k_scan(const int* __restrict__ cnt, int* __restrict__ off,
                       int* __restrict__ cur, float* __restrict__ dinv){
  __shared__ int wsum[16];
  __shared__ int carry_s;
  int tid = threadIdx.x;
  int lane = tid & 63, w = tid >> 6;
  int carry = 0;
  for (int base = 0; base < NN; base += 1024){
    int idx = base + tid;
    int v = (idx < NN) ? cnt[idx] : 0;
    int inc = v;
    for (int o2 = 1; o2 < 64; o2 <<= 1){
      int t = __shfl_up(inc, o2);
      if (lane >= o2) inc += t;
    }
    if (lane == 63) wsum[w] = inc;
    __syncthreads();                       // SYNC1
    if (tid < 16){
      int vv = wsum[tid], p = vv;
      for (int o2 = 1; o2 < 16; o2 <<= 1){
        int t = __shfl_up(p, o2, 16);
        if (tid >= o2) p += t;
      }
      wsum[tid] = p - vv;                  // exclusive wave offsets
    }
    __syncthreads();                       // SYNC2
    int ex = carry + wsum[w] + inc - v;
    if (idx < NN){
      off[idx] = ex; cur[idx] = ex;
      dinv[idx] = 1.0f / (float)(v > 1 ? v : 1);
    }
    if (tid == 1023) carry_s = carry + wsum[15] + inc;   // FIX: cumulative carry
    __syncthreads();                       // SYNC3
    carry = carry_s;
  }
  if (tid == 0) off[NN] = DE;
}

__global__ void k_fill(const int* __restrict__ ei, int* __restrict__ cur,
                       int* __restrict__ nbr, int* __restrict__ dstA, int* __restrict__ eid){
  int e = blockIdx.x*256 + threadIdx.x;
  if (e >= DE) return;
  int s, d, id;
  if (e < NE){ s = ei[e];  d = ei[NE + e]; id = e;      }
  else       { s = ei[e];  d = ei[e - NE]; id = e - NE; }
  int pos = atomicAdd(&cur[d], 1);
  nbr[pos] = s; dstA[pos] = d; eid[pos] = id;
}

// ---------------- weight pack to MFMA B-fragment order (bf16) ----------------
__global__ void k_pack(const float* __restrict__ nw1, const float* __restrict__ nw2,
                       const float* __restrict__ ew1, const float* __restrict__ ew2,
                       unsigned short* __restrict__ wp){
  int t = blockIdx.x*256 + threadIdx.x;
  if (t >= 98304) return;
  const float* src; int NO, p, base;
  if (t < 49152)      { int l = t/16384;            src = nw1 + l*16384; NO=128; p = t - l*16384;      base = t - p; }
  else if (t < 73728) { int q = t-49152; int l=q/8192; src = nw2 + l*8192; NO=64; p = q - l*8192;      base = t - p; }
  else if (t < 90112) {                              src = ew1;           NO=128; p = t - 73728;       base = 73728; }
  else                {                              src = ew2;           NO=64;  p = t - 90112;       base = 90112; }
  int f = p >> 9, r = p & 511, lane = r >> 3, i = r & 7;
  int NB = NO >> 4, kb = f / NB, nb = f - kb*NB;
  int k = kb*32 + ((lane >> 4) << 3) + i;
  int c = nb*16 + (lane & 15);
  wp[base + p] = f2bf(src[k*NO + c]);
}

// ---------------- node init: edge-slot-parallel gather + segmented reduce ----------------
__global__ __launch_bounds__(256,4) void k_init(
    const float* __restrict__ ef, const int* __restrict__ dstA,
    const int* __restrict__ eid, float* __restrict__ xsum)
{
  int lane = threadIdx.x & 63, wid = threadIdx.x >> 6;
  int tile = (blockIdx.x*4 + wid) * 32;
  if (tile >= DE) return;
  int q = lane >> 4, c4 = lane & 15;
  int dr = dstA[tile + (lane & 31)];
  int er = eid[tile + (lane & 31)];
  f32x4 v[8];
  #pragma unroll
  for (int it = 0; it < 8; it++){
    int row = q + it*4;
    int e = __shfl(er, row);
    v[it] = *(const f32x4*)(ef + (size_t)e*64 + c4*4);
  }
  int prev = __shfl_up(dr, 1);
  bool flag = (lane < 32) && (lane == 0 || dr != prev);
  unsigned long long mask = __ballot(flag);
  while (mask){
    int s = (int)__builtin_ctzll(mask);
    mask &= mask - 1;
    int e = mask ? (int)__builtin_ctzll(mask) : 32;
    int dseg = __shfl(dr, s);
    f32x4 p = {0,0,0,0};
    #pragma unroll
    for (int it = 0; it < 8; it++){
      int row = q + it*4;
      if ((unsigned)(row - s) < (unsigned)(e - s)) p += v[it];
    }
    #pragma unroll
    for (int k = 0; k < 4; k++){
      p[k] += __shfl_xor(p[k], 16);
      p[k] += __shfl_xor(p[k], 32);
    }
    if (q == 0){
      atomicAdd(&xsum[dseg*64 + c4*4 + 0], p[0]);
      atomicAdd(&xsum[dseg*64 + c4*4 + 1], p[1]);
      atomicAdd(&xsum[dseg*64 + c4*4 + 2], p[2]);
      atomicAdd(&xsum[dseg*64 + c4*4 + 3], p[3]);
    }
  }
}

// ---------------- x = xsum * dinv (init mean) ----------------
__global__ void k_div(const float* __restrict__ xsum, const float* __restrict__ dinv,
                      float* __restrict__ x, unsigned short* __restrict__ xbf){
  int n = blockIdx.x*4 + (threadIdx.x >> 6);
  int lane = threadIdx.x & 63;
  if (n >= NN) return;
  float v = xsum[n*64 + lane] * dinv[n];
  x[n*64 + lane] = v;
  xbf[n*64 + lane] = f2bf(v);
}

// ---------------- P/Q producer: node-level GEMM [NN,64]@[64,128] ----------------
__global__ __launch_bounds__(256,2) void k_pq(
    const unsigned short* __restrict__ xbf,
    const unsigned short* __restrict__ wp, int w1off,
    const float* __restrict__ bias,
    unsigned short* __restrict__ pb, unsigned short* __restrict__ qb)
{
  int lane = threadIdx.x & 63, wid = threadIdx.x >> 6;
  int tile = (blockIdx.x*4 + wid) * 32;
  if (tile >= NN) return;
  int r16 = lane & 15, g = lane >> 4;
  const svec8* w1g = (const svec8*)(wp + w1off);
  bfrag a[2][2];
  #pragma unroll
  for (int rb = 0; rb < 2; rb++){
    int n = tile + rb*16 + r16; if (n >= NN) n = NN-1;
    #pragma unroll
    for (int kb = 0; kb < 2; kb++)
      a[rb][kb] = __builtin_bit_cast(bfrag, *(const svec8*)(xbf + n*64 + kb*32 + g*8));
  }
  for (int ph = 0; ph < 2; ph++){
    f32x4 acc[8][2];
    #pragma unroll
    for (int nb = 0; nb < 8; nb++){ acc[nb][0] = (f32x4){0,0,0,0}; acc[nb][1] = (f32x4){0,0,0,0}; }
    #pragma unroll
    for (int kb = 0; kb < 2; kb++){
      #pragma unroll
      for (int nb = 0; nb < 8; nb++){
        bfrag b = __builtin_bit_cast(bfrag, w1g[((ph*2+kb)*8+nb)*64 + lane]);
        acc[nb][0] = MFMA(a[0][kb], b, acc[nb][0], 0, 0, 0);
        acc[nb][1] = MFMA(a[1][kb], b, acc[nb][1], 0, 0, 0);
      }
    }
    unsigned short* ob = ph ? qb : pb;
    #pragma unroll
    for (int nb = 0; nb < 8; nb++){
      float bv = (ph == 0) ? bias[nb*16 + r16] : 0.f;
      #pragma unroll
      for (int rb = 0; rb < 2; rb++){
        #pragma unroll
        for (int j = 0; j < 4; j++){
          int n = tile + rb*16 + g*4 + j;
          if (n < NN) ob[n*128 + nb*16 + r16] = f2bf(acc[nb][rb][j] + bv);
        }
      }
    }
  }
}

// ---------------- NodeConv: h=relu(P[dst]+Q[src]) in regs -> GEMM2 -> seg-reduce ----------------
__global__ __launch_bounds__(256,4) void k_conv(
    const unsigned short* __restrict__ pb, const unsigned short* __restrict__ qb,
    const int* __restrict__ cdst, const int* __restrict__ cnbr,
    const unsigned short* __restrict__ wp, int w2off,
    const float* __restrict__ b2, float* __restrict__ xsum)
{
  int lane = threadIdx.x & 63, wid = threadIdx.x >> 6;
  int tile = (blockIdx.x*4 + wid) * 32;
  if (tile >= DE) return;
  int r16 = lane & 15, g = lane >> 4;
  int dr = cdst[tile + (lane & 31)];
  int d0 = cdst[tile + r16],      d1 = cdst[tile + 16 + r16];
  int s0 = cnbr[tile + r16],      s1 = cnbr[tile + 16 + r16];
  const svec8* w2g = (const svec8*)(wp + w2off);

  f32x4 acc[4][2];
  #pragma unroll
  for (int nb = 0; nb < 4; nb++){ acc[nb][0] = (f32x4){0,0,0,0}; acc[nb][1] = (f32x4){0,0,0,0}; }

  #pragma unroll
  for (int kb = 0; kb < 4; kb++){
    int off = kb*32 + g*8;
    bfrag h0 = hbuild(pb + d0*128 + off, qb + s0*128 + off);
    bfrag h1 = hbuild(pb + d1*128 + off, qb + s1*128 + off);
    #pragma unroll
    for (int nb = 0; nb < 4; nb++){
      bfrag b = __builtin_bit_cast(bfrag, w2g[(kb*4+nb)*64 + lane]);
      acc[nb][0] = MFMA(h0, b, acc[nb][0], 0, 0, 0);
      acc[nb][1] = MFMA(h1, b, acc[nb][1], 0, 0, 0);
    }
  }
  float m[4][2][4];
  #pragma unroll
  for (int nb = 0; nb < 4; nb++){
    float bv = b2[nb*16 + r16];
    #pragma unroll
    for (int rb = 0; rb < 2; rb++){
      #pragma unroll
      for (int j = 0; j < 4; j++){
        float v = acc[nb][rb][j] + bv;
        m[nb][rb][j] = v > 0.f ? v : 0.f;
      }
    }
  }
  int prev = __shfl_up(dr, 1);
  bool flag = (lane < 32) && (lane == 0 || dr != prev);
  unsigned long long mask = __ballot(flag);
  while (mask){
    int s = (int)__builtin_ctzll(mask);
    mask &= mask - 1;
    int e = mask ? (int)__builtin_ctzll(mask) : 32;
    int dseg = __shfl(dr, s);
    float p0 = 0.f, p1 = 0.f, p2 = 0.f, p3 = 0.f;
    #pragma unroll
    for (int rb = 0; rb < 2; rb++){
      #pragma unroll
      for (int j = 0; j < 4; j++){
        int row = rb*16 + g*4 + j;
        if ((unsigned)(row - s) < (unsigned)(e - s)){
          p0 += m[0][rb][j]; p1 += m[1][rb][j]; p2 += m[2][rb][j]; p3 += m[3][rb][j];
        }
      }
    }
    p0 += __shfl_xor(p0, 16); p0 += __shfl_xor(p0, 32);
    p1 += __shfl_xor(p1, 16); p1 += __shfl_xor(p1, 32);
    p2 += __shfl_xor(p2, 16); p2 += __shfl_xor(p2, 32);
    p3 += __shfl_xor(p3, 16); p3 += __shfl_xor(p3, 32);
    if (g == 0){
      atomicAdd(&xsum[dseg*64 +      r16], p0);
      atomicAdd(&xsum[dseg*64 + 16 + r16], p1);
      atomicAdd(&xsum[dseg*64 + 32 + r16], p2);
      atomicAdd(&xsum[dseg*64 + 48 + r16], p3);
    }
  }
}

// ---------------- residual update: x += xsum * dinv ----------------
__global__ void k_finish(const float* __restrict__ xsum, const float* __restrict__ dinv,
                         float* __restrict__ x, unsigned short* __restrict__ xbf){
  int n = blockIdx.x*4 + (threadIdx.x >> 6);
  int lane = threadIdx.x & 63;
  if (n >= NN) return;
  float v = x[n*64 + lane] + xsum[n*64 + lane] * dinv[n];
  x[n*64 + lane] = v;
  xbf[n*64 + lane] = f2bf(v);
}

// ---------------- symmetric edge MLP via PE/QE ----------------
__global__ __launch_bounds__(256,4) void k_edge(
    const unsigned short* __restrict__ pe, const unsigned short* __restrict__ qe,
    const int* __restrict__ ei,
    const unsigned short* __restrict__ wp,
    const float* __restrict__ b2,
    float* __restrict__ outp, float* __restrict__ part)
{
  __shared__ float wred[4];
  int lane = threadIdx.x & 63, wid = threadIdx.x >> 6;
  int tile = (blockIdx.x*4 + wid) * 16;
  bool valid = tile < NE;
  int tl = valid ? tile : 0;
  int r16 = lane & 15, g = lane >> 4;
  const svec8* w2g = (const svec8*)(wp + 90112);
  int el = tl + r16;
  int sn = ei[el], dn = ei[NE + el];

  f32x4 acc[4][2];
  #pragma unroll
  for (int nb = 0; nb < 4; nb++){ acc[nb][0] = (f32x4){0,0,0,0}; acc[nb][1] = (f32x4){0,0,0,0}; }

  #pragma unroll
  for (int kb = 0; kb < 4; kb++){
    int off = kb*32 + g*8;
    bfrag h0 = hbuild(pe + sn*128 + off, qe + dn*128 + off);   // e1
    bfrag h1 = hbuild(pe + dn*128 + off, qe + sn*128 + off);   // e2
    #pragma unroll
    for (int nb = 0; nb < 4; nb++){
      bfrag b = __builtin_bit_cast(bfrag, w2g[(kb*4+nb)*64 + lane]);
      acc[nb][0] = MFMA(h0, b, acc[nb][0], 0, 0, 0);
      acc[nb][1] = MFMA(h1, b, acc[nb][1], 0, 0, 0);
    }
  }
  float lsum = 0.f;
  #pragma unroll
  for (int nb = 0; nb < 4; nb++){
    float bv = b2[nb*16 + r16];
    #pragma unroll
    for (int j = 0; j < 4; j++){
      float v1 = acc[nb][0][j] + bv;
      float v2 = acc[nb][1][j] + bv;
      int e = tile + g*4 + j;
      if (valid) outp[e*64 + nb*16 + r16] = 0.5f*(v1 + v2);
      float d = v1 - v2; lsum += d*d;
    }
  }
  if (!valid) lsum = 0.f;
  for (int o2 = 32; o2 > 0; o2 >>= 1) lsum += __shfl_down(lsum, o2);
  if (lane == 0) wred[wid] = lsum;
  __syncthreads();
  if (threadIdx.x == 0) part[blockIdx.x] = wred[0] + wred[1] + wred[2] + wred[3];
}

// ---------------- final loss reduction ----------------
__global__ void k_final(const float* __restrict__ part, float* __restrict__ outp){
  __shared__ float wred[16];
  int tid = threadIdx.x;
  float s = 0.f;
  for (int i = tid; i < NEB; i += 1024) s += part[i];
  for (int o2 = 32; o2 > 0; o2 >>= 1) s += __shfl_down(s, o2);
  int lane = tid & 63, w = tid >> 6;
  if (lane == 0) wred[w] = s;
  __syncthreads();
  if (tid == 0){
    float t = 0.f;
    #pragma unroll
    for (int i = 0; i < 16; i++) t += wred[i];
    outp[32000000] = t * (1.0f / 32000000.0f);
  }
}

// ---------------- launch ----------------
extern "C" void kernel_launch(void* const* d_in, const int* in_sizes, int n_in,
                              void* d_out, int out_size, void* d_ws, size_t ws_size,
                              hipStream_t stream)
{
  const float* ef  = (const float*)d_in[0];
  const int*   ei  = (const int*)  d_in[1];
  const float* nw1 = (const float*)d_in[2];
  const float* nb1 = (const float*)d_in[3];
  const float* nw2 = (const float*)d_in[4];
  const float* nb2 = (const float*)d_in[5];
  const float* ew1 = (const float*)d_in[6];
  const float* eb1 = (const float*)d_in[7];
  const float* ew2 = (const float*)d_in[8];
  const float* eb2 = (const float*)d_in[9];
  float* outp = (float*)d_out;

  char* ws = (char*)d_ws;
  size_t o = 0;
  auto alloc = [&](size_t b)->char*{ char* p = ws + o; o += (b + 255) & ~(size_t)255; return p; };
  int*   cnt  = (int*)  alloc((size_t)NN*4);
  int*   off  = (int*)  alloc((size_t)(NN+1)*4);
  int*   cur  = (int*)  alloc((size_t)NN*4);
  float* dinv = (float*)alloc((size_t)NN*4);
  int*   nbr  = (int*)  alloc((size_t)DE*4);
  int*   dstA = (int*)  alloc((size_t)DE*4);
  int*   eid  = (int*)  alloc((size_t)DE*4);
  float* x    = (float*)alloc((size_t)NN*64*4);
  unsigned short* xbf = (unsigned short*)alloc((size_t)NN*64*2);
  unsigned short* wp  = (unsigned short*)alloc((size_t)98304*2);
  float* part = (float*)alloc((size_t)NEB*4);
  unsigned short* pbuf = (unsigned short*)alloc((size_t)NN*128*2);
  unsigned short* qbuf = (unsigned short*)alloc((size_t)NN*128*2);
  float* xsI  = (float*)alloc((size_t)NN*64*4);
  float* xs0  = (float*)alloc((size_t)NN*64*4);
  float* xs1  = (float*)alloc((size_t)NN*64*4);
  float* xs2  = (float*)alloc((size_t)NN*64*4);
  float* xsum[3] = {xs0, xs1, xs2};

  hipMemsetAsync(cnt, 0, (size_t)NN*4, stream);
  hipMemsetAsync(xsI, 0, (size_t)NN*64*4, stream);
  hipMemsetAsync(xs0, 0, (size_t)NN*64*4, stream);
  hipMemsetAsync(xs1, 0, (size_t)NN*64*4, stream);
  hipMemsetAsync(xs2, 0, (size_t)NN*64*4, stream);
  k_hist<<<(DE+255)/256, 256, 0, stream>>>(ei, cnt);
  k_scan<<<1, 1024, 0, stream>>>(cnt, off, cur, dinv);
  k_fill<<<(DE+255)/256, 256, 0, stream>>>(ei, cur, nbr, dstA, eid);
  k_pack<<<384, 256, 0, stream>>>(nw1, nw2, ew1, ew2, wp);
  k_init<<<NEB, 256, 0, stream>>>(ef, dstA, eid, xsI);
  k_div<<<NN/4 + 1, 256, 0, stream>>>(xsI, dinv, x, xbf);
  for (int l = 0; l < 3; l++){
    k_pq<<<391, 256, 0, stream>>>(xbf, wp, l*16384, nb1 + l*128, pbuf, qbuf);
    k_conv<<<DE/128 + 1, 256, 0, stream>>>(pbuf, qbuf, dstA, nbr, wp,
                                           49152 + l*8192, nb2 + l*64, xsum[l]);
    k_finish<<<NN/4 + 1, 256, 0, stream>>>(xsum[l], dinv, x, xbf);
  }
  k_pq<<<391, 256, 0, stream>>>(xbf, wp, 73728, eb1, pbuf, qbuf);
  k_edge<<<NEB, 256, 0, stream>>>(pbuf, qbuf, ei, wp, eb2, outp, part);
  k_final<<<1, 1024, 0, stream>>>(part, outp);
}